// Round 12
// baseline (96.312 us; speedup 1.0000x reference)
//
#include <hip/hip_runtime.h>
#include <hip/hip_bf16.h>
#include <stdint.h>

#define NB    32
#define CIN   128
#define HIN   56
#define HW    (HIN*HIN)     // 3136
#define OCH   256
#define OHW   54
#define SPB   (OHW*OHW)     // 2916
#define KSZ   (CIN*9)       // 1152 = GEMM K
#define BM    256           // oc rows per block (= OCH)
#define BN    128           // flattened (n,sp) cols; 93312/128 = 729 exact
#define BK    32
#define NKS   (KSZ/BK)      // 36 K-tiles (even — loop unrolled by 2)
#define TOTC  (NB*SPB)      // 93312
#define NT    729
#define GRAN  1536          // (BM+BN)*4 granules (16B) per buffer = 24KB

typedef __attribute__((ext_vector_type(8))) short bf16x8;
typedef __attribute__((ext_vector_type(4))) float f32x4;

typedef __attribute__((address_space(1))) const uint32_t g_u32;
typedef __attribute__((address_space(3))) uint32_t l_u32;
static __device__ __forceinline__ void gl_lds16(const void* g, void* l) {
    __builtin_amdgcn_global_load_lds((g_u32*)g, (l_u32*)l, 16, 0, 0);
}

// ---- pre-pass 1: x NCHW f32 -> NHWC bf16 ----
__global__ void xpose_cast(const float* __restrict__ x, __hip_bfloat16* __restrict__ xt) {
    __shared__ float tile[32][33];
    const int hw0 = blockIdx.x * 32;
    const int c0  = blockIdx.y * 32;
    const int n   = blockIdx.z;
    const int tx = threadIdx.x, ty = threadIdx.y;
    const float* xp = x + ((size_t)n*CIN + c0)*HW + hw0;
    #pragma unroll
    for (int i = ty; i < 32; i += 8)
        tile[i][tx] = xp[(size_t)i*HW + tx];
    __syncthreads();
    const int t = ty*32 + tx;
    const int hwl = t >> 3, q = t & 7;
    ushort4 v;
    v.x = __bfloat16_as_ushort(__float2bfloat16(tile[q*4+0][hwl]));
    v.y = __bfloat16_as_ushort(__float2bfloat16(tile[q*4+1][hwl]));
    v.z = __bfloat16_as_ushort(__float2bfloat16(tile[q*4+2][hwl]));
    v.w = __bfloat16_as_ushort(__float2bfloat16(tile[q*4+3][hwl]));
    __hip_bfloat16* op = xt + ((size_t)n*HW + hw0 + hwl)*CIN + c0 + q*4;
    *(ushort4*)op = v;
}

// ---- pre-pass 2: weight OIHW f32 -> [oc][(kh*3+kw)*128+ic] bf16 ----
__global__ void wcast(const float* __restrict__ w, __hip_bfloat16* __restrict__ wt) {
    int tid = blockIdx.x*256 + threadIdx.x;
    if (tid >= OCH*KSZ) return;
    int oc = tid / KSZ, r = tid % KSZ;
    int pos = r >> 7, ic = r & 127;
    wt[tid] = __float2bfloat16(w[((size_t)(oc*CIN + ic))*9 + pos]);
}

// ---- main: implicit-GEMM bf16 MFMA conv, register-rotated pipeline ----
// grid (729), block 256 = 4 waves (2M x 2N), per-wave 128x64 (acc 8x4).
// BK=32, triple buffer 72KB (2 blocks/CU). Per half-iteration: certify + barrier,
// stage(t+2), ds_read frags(t+1), lgkm(8) [retires tile t's reads: ~0 wait],
// MFMA(t) from LAST half's registers -> read latency hides under MFMA pipe.
__global__ __launch_bounds__(256, 2)
void conv_mfma(const __hip_bfloat16* __restrict__ xt,
               const __hip_bfloat16* __restrict__ wt,
               const float* __restrict__ bias,
               float* __restrict__ out) {
    __shared__ uint4 smem[3*GRAN];   // 73728 B

    const int t = threadIdx.x;
    // bijective XCD swizzle: nwg=729 = 8*91+1 -> q=91, r=1
    const int orig = blockIdx.x;
    const int xcd = orig & 7;
    const int tile = (xcd < 1 ? xcd*92 : 92 + (xcd-1)*91) + (orig >> 3);

    const int lane = t & 63, wid = t >> 6;
    const int wm = wid >> 1, wn = wid & 1;     // per-wave 128 rows x 64 cols
    const int lr = lane & 15, lq = lane >> 4;

    // staging sources (round-11 layout: slot j holds k-chunk j ^ ((row>>1)&3))
    const __hip_bfloat16* asrc[4];
    #pragma unroll
    for (int i = 0; i < 4; ++i) {
        int q = i*256 + t;
        int row = q >> 2, j = q & 3;
        int ls = j ^ ((row >> 1) & 3);
        asrc[i] = wt + (size_t)row*KSZ + ls*8;
    }
    const __hip_bfloat16* bsrc[2];
    #pragma unroll
    for (int i = 0; i < 2; ++i) {
        int q = i*256 + t;
        int col = q >> 2, j = q & 3;
        int ls = j ^ ((col >> 1) & 3);
        int colg = tile*BN + col;
        int n = colg / SPB, rem = colg - n*SPB;
        int oh = rem / OHW, ow = rem - oh*OHW;
        bsrc[i] = xt + ((size_t)(n*HIN + oh)*HIN + ow)*CIN + ls*8;
    }

    auto issueT = [&](uint4* dst, int ks) {    // 6 gl_lds: tile ks -> dst buffer
        const int aoff = ks*BK;
        const int pos = ks >> 2;
        const int kh = pos / 3, kw = pos - kh*3;
        const int boff = (kh*HIN + kw)*CIN + (ks & 3)*32;
        #pragma unroll
        for (int i = 0; i < 4; ++i) gl_lds16(asrc[i] + aoff, dst + i*256 + t);
        #pragma unroll
        for (int i = 0; i < 2; ++i) gl_lds16(bsrc[i] + boff, dst + 1024 + i*256 + t);
    };

    // per-lane read offsets (granule units)
    int ao[8], bo[4];
    #pragma unroll
    for (int mi = 0; mi < 8; ++mi) {
        int ra = wm*128 + mi*16 + lr;
        ao[mi] = ra*4 + (lq ^ ((ra >> 1) & 3));
    }
    #pragma unroll
    for (int ni = 0; ni < 4; ++ni) {
        int cb = wn*64 + ni*16 + lr;
        bo[ni] = 1024 + cb*4 + (lq ^ ((cb >> 1) & 3));
    }

    f32x4 acc[8][4];
    #pragma unroll
    for (int i = 0; i < 8; ++i)
        #pragma unroll
        for (int j = 0; j < 4; ++j)
            acc[i][j] = (f32x4){0.f, 0.f, 0.f, 0.f};

    #define MFMA_BF16 __builtin_amdgcn_mfma_f32_16x16x32_bf16
    #define RD_AABB(AA, BB, P) \
        _Pragma("unroll") for (int mi = 0; mi < 4; ++mi) AA[mi] = *(bf16x8*)&(P)[ao[mi]]; \
        _Pragma("unroll") for (int ni = 0; ni < 4; ++ni) BB[ni] = *(bf16x8*)&(P)[bo[ni]];
    #define RD_AB(AB, P) \
        _Pragma("unroll") for (int mi = 0; mi < 4; ++mi) AB[mi] = *(bf16x8*)&(P)[ao[4 + mi]];
    #define MFMA16LO(AA, BB) \
        _Pragma("unroll") for (int mi = 0; mi < 4; ++mi) \
            _Pragma("unroll") for (int ni = 0; ni < 4; ++ni) \
                acc[mi][ni] = MFMA_BF16(AA[mi], BB[ni], acc[mi][ni], 0, 0, 0);
    #define MFMA16HI(AB, BB) \
        _Pragma("unroll") for (int mi = 0; mi < 4; ++mi) \
            _Pragma("unroll") for (int ni = 0; ni < 4; ++ni) \
                acc[4+mi][ni] = MFMA_BF16(AB[mi], BB[ni], acc[4+mi][ni], 0, 0, 0);
    #define SCHEDB __builtin_amdgcn_sched_barrier(0)

    uint4 *bcur = smem, *bnext = smem + GRAN, *bthird = smem + 2*GRAN;
    bf16x8 aaE[4], abE[4], bbE[4];   // even-half set
    bf16x8 aaO[4], abO[4], bbO[4];   // odd-half set

    // prologue: stage tiles 0,1; certify 0; read tile 0 frags into even set
    issueT(bcur, 0); issueT(bnext, 1);
    asm volatile("s_waitcnt vmcnt(6)" ::: "memory");
    __builtin_amdgcn_s_barrier();
    SCHEDB;
    RD_AABB(aaE, bbE, bcur)
    RD_AB(abE, bcur)

    for (int ks = 0; ks < NKS; ks += 2) {
        // ---- half A: MFMA tile ks (even set); read tile ks+1 -> odd set ----
        asm volatile("s_waitcnt vmcnt(0)" ::: "memory");   // buf[ks+1] landed (staged ~1 half ago)
        __builtin_amdgcn_s_barrier();                      // all waves: reads of buf[ks+2 slot] retired
        SCHEDB;
        if (ks + 2 < NKS) issueT(bthird, ks + 2);
        RD_AABB(aaO, bbO, bnext)
        asm volatile("s_waitcnt lgkmcnt(8)" ::: "memory"); // tile ks's 12 reads done (old)
        SCHEDB;
        MFMA16LO(aaE, bbE)
        RD_AB(abO, bnext)
        MFMA16HI(abE, bbE)
        { uint4* tmp = bcur; bcur = bnext; bnext = bthird; bthird = tmp; }

        // ---- half B: MFMA tile ks+1 (odd set); read tile ks+2 -> even set ----
        asm volatile("s_waitcnt vmcnt(0)" ::: "memory");
        __builtin_amdgcn_s_barrier();
        SCHEDB;
        if (ks + 3 < NKS) issueT(bthird, ks + 3);
        if (ks + 2 < NKS) {
            RD_AABB(aaE, bbE, bnext)
            asm volatile("s_waitcnt lgkmcnt(8)" ::: "memory");
        } else {
            asm volatile("s_waitcnt lgkmcnt(0)" ::: "memory");
        }
        SCHEDB;
        MFMA16LO(aaO, bbO)
        if (ks + 2 < NKS) { RD_AB(abE, bnext) }
        MFMA16HI(abO, bbO)
        { uint4* tmp = bcur; bcur = bnext; bnext = bthird; bthird = tmp; }
    }

    __syncthreads();

    // --- epilogue: LDS restage [64][132] (2-way free), coalesced float4 stores ---
    float (*eps)[132] = (float (*)[132])smem;
    const int cl4 = (t & 31) * 4;                 // 0..124
    const int rsub = t >> 5;                      // 0..7
    const int colg = tile*BN + cl4;
    const int nn = colg / SPB;
    const int sp = colg - nn*SPB;                 // SPB%4==0 -> no straddle
    #pragma unroll
    for (int h = 0; h < 4; ++h) {
        if (wm == (h >> 1)) {
            const int mib = (h & 1) * 4;
            #pragma unroll
            for (int ii = 0; ii < 4; ++ii) {
                int rl = ii*16 + lq*4;
                #pragma unroll
                for (int ni = 0; ni < 4; ++ni) {
                    int cl = wn*64 + ni*16 + lr;
                    #pragma unroll
                    for (int r = 0; r < 4; ++r)
                        eps[rl + r][cl] = acc[mib + ii][ni][r];
                }
            }
        }
        __syncthreads();
        {
            #pragma unroll
            for (int pass = 0; pass < 8; ++pass) {
                int rl = pass*8 + rsub;
                int rg = h*64 + rl;
                f32x4 v = *(f32x4*)&eps[rl][cl4];
                v = v + bias[rg];
                *(f32x4*)&out[((size_t)nn*OCH + rg)*SPB + sp] = v;
            }
        }
        __syncthreads();
    }
}

// ---- fallback: direct fp32 conv ----
__global__ void conv_naive(const float* __restrict__ x, const float* __restrict__ w,
                           const float* __restrict__ bias, float* __restrict__ out) {
    size_t tid = (size_t)blockIdx.x*256 + threadIdx.x;
    const size_t total = (size_t)NB*OCH*SPB;
    if (tid >= total) return;
    int col = (int)(tid % SPB);
    int oc  = (int)((tid / SPB) % OCH);
    int n   = (int)(tid / ((size_t)SPB*OCH));
    int oh = col / OHW, ow = col % OHW;
    float s = bias[oc];
    for (int ic = 0; ic < CIN; ++ic)
        #pragma unroll
        for (int kh = 0; kh < 3; ++kh)
            #pragma unroll
            for (int kw = 0; kw < 3; ++kw)
                s += x[((size_t)(n*CIN+ic)*HIN + oh+kh)*HIN + ow+kw]
                   * w[((size_t)(oc*CIN+ic)*3 + kh)*3 + kw];
    out[tid] = s;
}

extern "C" void kernel_launch(void* const* d_in, const int* in_sizes, int n_in,
                              void* d_out, int out_size, void* d_ws, size_t ws_size,
                              hipStream_t stream) {
    const float* x    = (const float*)d_in[0];
    const float* w    = (const float*)d_in[1];
    const float* bias = (const float*)d_in[2];
    float* out = (float*)d_out;

    const size_t xt_bytes = (size_t)NB*HW*CIN*sizeof(__hip_bfloat16);
    const size_t wt_bytes = (size_t)OCH*KSZ*sizeof(__hip_bfloat16);

    if (ws_size >= xt_bytes + wt_bytes) {
        __hip_bfloat16* xt  = (__hip_bfloat16*)d_ws;
        __hip_bfloat16* wtp = (__hip_bfloat16*)((char*)d_ws + xt_bytes);
        hipLaunchKernelGGL(xpose_cast, dim3(HW/32, CIN/32, NB), dim3(32, 8), 0, stream, x, xt);
        hipLaunchKernelGGL(wcast, dim3((OCH*KSZ + 255)/256), dim3(256), 0, stream, w, wtp);
        hipLaunchKernelGGL(conv_mfma, dim3(NT), dim3(256), 0, stream, xt, wtp, bias, out);
    } else {
        size_t total = (size_t)NB*OCH*SPB;
        hipLaunchKernelGGL(conv_naive, dim3((unsigned)((total + 255)/256)), dim3(256), 0, stream,
                           x, w, bias, out);
    }
}